// Round 3
// baseline (221.724 us; speedup 1.0000x reference)
//
#include <hip/hip_runtime.h>

// Problem constants
#define V_N 1000000
#define J_N 23
#define BLK 256
#define NT_TILES 3907       // 3906 full 256-vertex tiles + 1 tail tile (64 verts)
#define GRID2 1536          // 6 blocks/CU * 256 CU: fully resident, grid-stride over tiles

// Output layout (flat fp32-element offsets):
// verts_batched (4,V,3) | pose (J,3) | joints_out (J,3) | scale (1) | displacement (3) | local_adjust (V,3)
#define OUT_POSE   12000000
#define OUT_JOINTS 12000069
#define OUT_SCALE  12000138
#define OUT_DISP   12000139
#define OUT_LA     12000142   // byte 48000568: 8B-aligned, NOT 16B-aligned

__device__ __constant__ int c_parents[J_N] = {
    -1, 0, 1, 1, 3, 4, 5, 4, 7, 4, 9, 1, 11, 12, 13, 12, 15, 12, 17, 0, 19, 0, 21
};

// ---------------- Stage 1: pose / Rodrigues / FK chain (tiny, 1 block) ----------------
__global__ void stage1_kernel(
    const float* __restrict__ joints_rest,
    const float* __restrict__ j0, const float* __restrict__ j1,
    const float* __restrict__ j2, const float* __restrict__ j3,
    const float* __restrict__ j4, const float* __restrict__ j5,
    const float* __restrict__ j12, const float* __restrict__ j13,
    const float* __restrict__ disp, const float* __restrict__ scale,
    const float* __restrict__ loc,
    float* __restrict__ wsA, float* __restrict__ out)
{
    __shared__ float jr[J_N][3];
    __shared__ float pose[J_N][3];
    __shared__ float R[J_N][9];
    __shared__ float rel[J_N][3];
    __shared__ float G[J_N][12];
    __shared__ float sb[4];
    const int t = threadIdx.x;

    if (t < J_N * 3) {
        ((float*)jr)[t]   = joints_rest[t];
        ((float*)pose)[t] = 0.0f;
    }
    __syncthreads();

    if (t < 27) {   // one thread per (pose row, component)
        const float PI = 3.14159265358979323846f;
        const int   rows[9] = { 0, 1, 2, 3, 11, 4, 5, 12, 13 };
        const float cf[9]   = { PI/2, PI/4, PI/9, PI/3, PI/3, PI/3, PI/3, PI/3, PI/3 };
        int i = t / 3, cmp = t % 3;
        const float* srcs[9];
        srcs[0]=j0; srcs[1]=j1; srcs[2]=j2; srcs[3]=j3; srcs[4]=j3;
        srcs[5]=j4; srcs[6]=j5; srcs[7]=j12; srcs[8]=j13;
        float syz = (rows[i] == 11 && cmp > 0) ? -1.0f : 1.0f;
        pose[rows[i]][cmp] = cf[i] * syz * tanhf(srcs[i][cmp]);
    }
    if (t == 32) {
        sb[0] = 0.0035f * scale[0];
        sb[1] = loc[0] + 0.1f * tanhf(disp[0]);
        sb[2] = loc[1] + 0.1f * tanhf(disp[1]);
        sb[3] = loc[2] + 0.1f * tanhf(disp[2]);
    }
    __syncthreads();

    if (t < J_N) {
        float rx = pose[t][0], ry = pose[t][1], rz = pose[t][2];
        float ang = sqrtf(rx*rx + ry*ry + rz*rz + 1e-12f);
        float inv = 1.0f / ang;
        float x = rx * inv, y = ry * inv, z = rz * inv;
        float s = sinf(ang), c = cosf(ang);
        float K[9]  = { 0.f, -z, y,  z, 0.f, -x,  -y, x, 0.f };
        float K2[9];
        for (int r = 0; r < 3; r++)
            for (int cc = 0; cc < 3; cc++) {
                float a = 0.f;
                for (int k = 0; k < 3; k++) a += K[r*3+k] * K[k*3+cc];
                K2[r*3+cc] = a;
            }
        for (int r = 0; r < 3; r++)
            for (int cc = 0; cc < 3; cc++) {
                float id = (r == cc) ? 1.f : 0.f;
                R[t][r*3+cc] = id + s * K[r*3+cc] + (1.f - c) * K2[r*3+cc];
            }
        int p = c_parents[t];
        for (int cc = 0; cc < 3; cc++)
            rel[t][cc] = (p < 0) ? jr[t][cc] : (jr[t][cc] - jr[p][cc]);
    }
    __syncthreads();

    if (t == 0) {  // serial FK chain (parents precede children)
        for (int r = 0; r < 3; r++) {
            for (int cc = 0; cc < 3; cc++) G[0][r*4+cc] = R[0][r*3+cc];
            G[0][r*4+3] = rel[0][r];
        }
        for (int j = 1; j < J_N; j++) {
            int p = c_parents[j];
            for (int r = 0; r < 3; r++) {
                float g0 = G[p][r*4+0], g1 = G[p][r*4+1], g2 = G[p][r*4+2], g3 = G[p][r*4+3];
                for (int cc = 0; cc < 3; cc++)
                    G[j][r*4+cc] = g0*R[j][0*3+cc] + g1*R[j][1*3+cc] + g2*R[j][2*3+cc];
                G[j][r*4+3] = g0*rel[j][0] + g1*rel[j][1] + g2*rel[j][2] + g3;
            }
        }
    }
    __syncthreads();

    if (t < J_N) {
        for (int r = 0; r < 3; r++) {
            float tc = G[t][r*4+0]*jr[t][0] + G[t][r*4+1]*jr[t][1] + G[t][r*4+2]*jr[t][2];
            wsA[t*12 + r*4 + 0] = G[t][r*4+0];
            wsA[t*12 + r*4 + 1] = G[t][r*4+1];
            wsA[t*12 + r*4 + 2] = G[t][r*4+2];
            wsA[t*12 + r*4 + 3] = G[t][r*4+3] - tc;
            out[OUT_JOINTS + t*3 + r] = sb[0] * G[t][r*4+3] + sb[1+r];
        }
    }
    if (t < J_N * 3) out[OUT_POSE + t] = ((const float*)pose)[t];
    if (t == 0) {
        wsA[276] = sb[0]; wsA[277] = sb[1]; wsA[278] = sb[2]; wsA[279] = sb[3];
        out[OUT_SCALE]  = scale[0];
        out[OUT_DISP+0] = disp[0]; out[OUT_DISP+1] = disp[1]; out[OUT_DISP+2] = disp[2];
    }
}

// ---------------- Stage 2: per-vertex skinning ----------------
// Wave-autonomous software pipeline (round-1 design, round-2 hardening: all
// conditionally-consumed registers are zero-initialized -> no UB anywhere).
//  - Each of the 4 waves owns a private 5888 B LDS slice -> NO __syncthreads
//    anywhere (waves never couple; LDS ops are in-order per wave).
//  - Persistent grid (1536 blocks = 6/CU, fully resident), grid-stride over
//    3907 tiles. While computing tile t from LDS, the wave has already issued
//    tile t+1's global loads into registers; the ds_write of t+1 happens after
//    the compute, its vmcnt wait hidden under the 276-FMA body.
//  - V_N is a multiple of 64, so every wave is either fully active for a tile
//    or fully inactive (tail tile 3906: only wave 0 active).
// NO launch_bounds (min-waves directive triggered scratch spilling on this
// toolchain in the earlier session -> 13x HBM traffic).
__global__ void stage2_kernel(
    const float* __restrict__ vt,     // v_template   V*3 f32
    const float* __restrict__ skin,   // skinning     V*J f32
    const float* __restrict__ la,     // local_adjust V*3 f32
    const float* __restrict__ wsA,    // A[23][12] + {s, base.xyz}  (uniform reads)
    const int* __restrict__ bsp,      // batch_size
    float* __restrict__ out)
{
    __shared__ uint4 s_sk[4][368];    // 23552 B total -> 6 blocks/CU; per-wave slices

    const int tid  = threadIdx.x;
    const int lane = tid & 63;
    const int w    = tid >> 6;
    uint4* const slice = s_sk[w];
    const float* const wsl = (const float*)s_sk[w];

    const float sc = wsA[276];                  // uniform -> SGPR
    const float bx = wsA[277], by = wsA[278], bz = wsA[279];
    const int   bsz = bsp[0];

    int t = blockIdx.x;                         // < 1536 -> prologue always active
    float cvx = 0.f, cvy = 0.f, cvz = 0.f, clx = 0.f, cly = 0.f, clz = 0.f;

    // ---- prologue: stage tile t (t < 1536 -> always a full tile) ----
    {
        const int vb = t * 256 + (w << 6);
        const uint4* g = (const uint4*)(skin + (size_t)vb * 23);
        uint4 r0 = g[lane];
        uint4 r1 = g[lane + 64];
        uint4 r2 = g[lane + 128];
        uint4 r3 = g[lane + 192];
        uint4 r4 = g[lane + 256];
        uint4 r5 = make_uint4(0u, 0u, 0u, 0u);
        if (lane < 48) r5 = g[lane + 320];
        const float* vp = vt + (size_t)(vb + lane) * 3;
        const float* lp = la + (size_t)(vb + lane) * 3;
        cvx = vp[0]; cvy = vp[1]; cvz = vp[2];
        clx = lp[0]; cly = lp[1]; clz = lp[2];
        slice[lane]       = r0;
        slice[lane + 64]  = r1;
        slice[lane + 128] = r2;
        slice[lane + 192] = r3;
        slice[lane + 256] = r4;
        if (lane < 48) slice[lane + 320] = r5;
    }

    for (;;) {
        // ---- issue next tile's loads (registers only; no wait here) ----
        const int tn  = t + GRID2;
        const int vbn = tn * 256 + (w << 6);
        const bool actn = (tn < NT_TILES) && (vbn < V_N);
        uint4 n0 = make_uint4(0u,0u,0u,0u), n1 = n0, n2 = n0, n3 = n0, n4 = n0, n5 = n0;
        float nvx = 0.f, nvy = 0.f, nvz = 0.f, nlx = 0.f, nly = 0.f, nlz = 0.f;
        if (actn) {
            const uint4* g = (const uint4*)(skin + (size_t)vbn * 23);
            n0 = g[lane];
            n1 = g[lane + 64];
            n2 = g[lane + 128];
            n3 = g[lane + 192];
            n4 = g[lane + 256];
            if (lane < 48) n5 = g[lane + 320];
            const float* vp = vt + (size_t)(vbn + lane) * 3;
            const float* lp = la + (size_t)(vbn + lane) * 3;
            nvx = vp[0]; nvy = vp[1]; nvz = vp[2];
            nlx = lp[0]; nly = lp[1]; nlz = lp[2];
        }

        // ---- compute current tile from this wave's LDS slice ----
        const int vb = t * 256 + (w << 6);
        if (vb < V_N) {
            const int v = vb + lane;
            const float* wr = wsl + lane * J_N;   // stride 23: 2-way alias, free
            float acc[12];
            #pragma unroll
            for (int k = 0; k < 12; k++) acc[k] = 0.f;
            #pragma unroll
            for (int j = 0; j < J_N; j++) {
                const float wj = wr[j];
                const float* Aj = wsA + j * 12;   // uniform address -> s_load, 0 VGPRs
                #pragma unroll
                for (int k = 0; k < 12; k++) acc[k] = fmaf(wj, Aj[k], acc[k]);
            }
            const float vx = cvx + 0.1f * tanhf(clx);
            const float vy = cvy + 0.1f * tanhf(cly);
            const float vz = cvz + 0.1f * tanhf(clz);
            const float px = acc[0]*vx + acc[1]*vy + acc[2]*vz  + acc[3];
            const float py = acc[4]*vx + acc[5]*vy + acc[6]*vz  + acc[7];
            const float pz = acc[8]*vx + acc[9]*vy + acc[10]*vz + acc[11];
            const float ox = fmaf(sc, px, bx);
            const float oy = fmaf(sc, py, by);
            const float oz = fmaf(sc, pz, bz);

            float* ob = out + (size_t)v * 3;
            for (int b = 0; b < bsz; b++) {
                ob[0] = ox; ob[1] = oy; ob[2] = oz;   // dwordx3, coalesced
                ob += 3000000;                        // V*3 floats per batch copy
            }
            float* oe = out + OUT_LA + (size_t)v * 3; // local_adjust passthrough
            oe[0] = clx; oe[1] = cly; oe[2] = clz;
        }

        if (tn >= NT_TILES) break;

        // ---- stage next tile (vmcnt wait covered by the compute above;
        //      ds_writes ordered after this wave's ds_reads by program order) ----
        if (actn) {
            slice[lane]       = n0;
            slice[lane + 64]  = n1;
            slice[lane + 128] = n2;
            slice[lane + 192] = n3;
            slice[lane + 256] = n4;
            if (lane < 48) slice[lane + 320] = n5;
            cvx = nvx; cvy = nvy; cvz = nvz;
            clx = nlx; cly = nly; clz = nlz;
        }
        t = tn;
    }
}

extern "C" void kernel_launch(void* const* d_in, const int* in_sizes, int n_in,
                              void* d_out, int out_size, void* d_ws, size_t ws_size,
                              hipStream_t stream) {
    const float* vt   = (const float*)d_in[0];
    const float* skin = (const float*)d_in[1];
    const float* jr   = (const float*)d_in[2];
    const float* j0   = (const float*)d_in[3];
    const float* j1   = (const float*)d_in[4];
    const float* j2   = (const float*)d_in[5];
    const float* j3   = (const float*)d_in[6];
    const float* j4   = (const float*)d_in[7];
    const float* j5   = (const float*)d_in[8];
    const float* j12  = (const float*)d_in[9];
    const float* j13  = (const float*)d_in[10];
    const float* la   = (const float*)d_in[11];
    const float* disp = (const float*)d_in[12];
    const float* sc   = (const float*)d_in[13];
    const float* loc  = (const float*)d_in[14];
    const int* bs     = (const int*)d_in[15];

    float* wsA = (float*)d_ws;
    float* out = (float*)d_out;

    stage1_kernel<<<1, 128, 0, stream>>>(jr, j0, j1, j2, j3, j4, j5, j12, j13,
                                         disp, sc, loc, wsA, out);
    stage2_kernel<<<GRID2, BLK, 0, stream>>>(vt, skin, la, wsA, bs, out);
}

// Round 4
// 215.969 us; speedup vs baseline: 1.0266x; 1.0266x over previous
//
#include <hip/hip_runtime.h>

// Problem constants
#define V_N 1000000
#define J_N 23
#define BLK 256

// Output layout (flat fp32-element offsets):
// verts_batched (4,V,3) | pose (J,3) | joints_out (J,3) | scale (1) | displacement (3) | local_adjust (V,3)
#define OUT_POSE   12000000
#define OUT_JOINTS 12000069
#define OUT_SCALE  12000138
#define OUT_DISP   12000139
#define OUT_LA     12000142   // byte 48000568: 8B-aligned, NOT 16B-aligned

__device__ __constant__ int c_parents[J_N] = {
    -1, 0, 1, 1, 3, 4, 5, 4, 7, 4, 9, 1, 11, 12, 13, 12, 15, 12, 17, 0, 19, 0, 21
};

// ---------------- Stage 1: pose / Rodrigues / FK chain (tiny, 1 block) ----------------
__global__ void stage1_kernel(
    const float* __restrict__ joints_rest,
    const float* __restrict__ j0, const float* __restrict__ j1,
    const float* __restrict__ j2, const float* __restrict__ j3,
    const float* __restrict__ j4, const float* __restrict__ j5,
    const float* __restrict__ j12, const float* __restrict__ j13,
    const float* __restrict__ disp, const float* __restrict__ scale,
    const float* __restrict__ loc,
    float* __restrict__ wsA, float* __restrict__ out)
{
    __shared__ float jr[J_N][3];
    __shared__ float pose[J_N][3];
    __shared__ float R[J_N][9];
    __shared__ float rel[J_N][3];
    __shared__ float G[J_N][12];
    __shared__ float sb[4];
    const int t = threadIdx.x;

    if (t < J_N * 3) {
        ((float*)jr)[t]   = joints_rest[t];
        ((float*)pose)[t] = 0.0f;
    }
    __syncthreads();

    if (t < 27) {   // one thread per (pose row, component)
        const float PI = 3.14159265358979323846f;
        const int   rows[9] = { 0, 1, 2, 3, 11, 4, 5, 12, 13 };
        const float cf[9]   = { PI/2, PI/4, PI/9, PI/3, PI/3, PI/3, PI/3, PI/3, PI/3 };
        int i = t / 3, cmp = t % 3;
        const float* srcs[9];
        srcs[0]=j0; srcs[1]=j1; srcs[2]=j2; srcs[3]=j3; srcs[4]=j3;
        srcs[5]=j4; srcs[6]=j5; srcs[7]=j12; srcs[8]=j13;
        float syz = (rows[i] == 11 && cmp > 0) ? -1.0f : 1.0f;
        pose[rows[i]][cmp] = cf[i] * syz * tanhf(srcs[i][cmp]);
    }
    if (t == 32) {
        sb[0] = 0.0035f * scale[0];
        sb[1] = loc[0] + 0.1f * tanhf(disp[0]);
        sb[2] = loc[1] + 0.1f * tanhf(disp[1]);
        sb[3] = loc[2] + 0.1f * tanhf(disp[2]);
    }
    __syncthreads();

    if (t < J_N) {
        float rx = pose[t][0], ry = pose[t][1], rz = pose[t][2];
        float ang = sqrtf(rx*rx + ry*ry + rz*rz + 1e-12f);
        float inv = 1.0f / ang;
        float x = rx * inv, y = ry * inv, z = rz * inv;
        float s = sinf(ang), c = cosf(ang);
        float K[9]  = { 0.f, -z, y,  z, 0.f, -x,  -y, x, 0.f };
        float K2[9];
        for (int r = 0; r < 3; r++)
            for (int cc = 0; cc < 3; cc++) {
                float a = 0.f;
                for (int k = 0; k < 3; k++) a += K[r*3+k] * K[k*3+cc];
                K2[r*3+cc] = a;
            }
        for (int r = 0; r < 3; r++)
            for (int cc = 0; cc < 3; cc++) {
                float id = (r == cc) ? 1.f : 0.f;
                R[t][r*3+cc] = id + s * K[r*3+cc] + (1.f - c) * K2[r*3+cc];
            }
        int p = c_parents[t];
        for (int cc = 0; cc < 3; cc++)
            rel[t][cc] = (p < 0) ? jr[t][cc] : (jr[t][cc] - jr[p][cc]);
    }
    __syncthreads();

    if (t == 0) {  // serial FK chain (parents precede children)
        for (int r = 0; r < 3; r++) {
            for (int cc = 0; cc < 3; cc++) G[0][r*4+cc] = R[0][r*3+cc];
            G[0][r*4+3] = rel[0][r];
        }
        for (int j = 1; j < J_N; j++) {
            int p = c_parents[j];
            for (int r = 0; r < 3; r++) {
                float g0 = G[p][r*4+0], g1 = G[p][r*4+1], g2 = G[p][r*4+2], g3 = G[p][r*4+3];
                for (int cc = 0; cc < 3; cc++)
                    G[j][r*4+cc] = g0*R[j][0*3+cc] + g1*R[j][1*3+cc] + g2*R[j][2*3+cc];
                G[j][r*4+3] = g0*rel[j][0] + g1*rel[j][1] + g2*rel[j][2] + g3;
            }
        }
    }
    __syncthreads();

    if (t < J_N) {
        for (int r = 0; r < 3; r++) {
            float tc = G[t][r*4+0]*jr[t][0] + G[t][r*4+1]*jr[t][1] + G[t][r*4+2]*jr[t][2];
            wsA[t*12 + r*4 + 0] = G[t][r*4+0];
            wsA[t*12 + r*4 + 1] = G[t][r*4+1];
            wsA[t*12 + r*4 + 2] = G[t][r*4+2];
            wsA[t*12 + r*4 + 3] = G[t][r*4+3] - tc;
            out[OUT_JOINTS + t*3 + r] = sb[0] * G[t][r*4+3] + sb[1+r];
        }
    }
    if (t < J_N * 3) out[OUT_POSE + t] = ((const float*)pose)[t];
    if (t == 0) {
        wsA[276] = sb[0]; wsA[277] = sb[1]; wsA[278] = sb[2]; wsA[279] = sb[3];
        out[OUT_SCALE]  = scale[0];
        out[OUT_DISP+0] = disp[0]; out[OUT_DISP+1] = disp[1]; out[OUT_DISP+2] = disp[2];
    }
}

// ---------------- Stage 2: per-vertex skinning ----------------
// Round-4 restructure: kill the lgkmcnt mixing that was the invariant wall
// across rounds 0/1/3 (ds_read weights + s_load A share lgkmcnt and return
// out-of-order w.r.t. each other -> per-j conservative drains inside the FMA
// stream; VALUBusy stuck at 10-14% regardless of staging scheme).
//  - NO LDS at all. Each lane loads its own 23 weights global->VGPR as 23
//    independent dword loads (base v*92 B: every offset 4B-aligned). These are
//    vmcnt-counted; the compiler staggers precise vmcnt(N) waits through the
//    FMA stream.
//  - lgkmcnt now carries ONLY the A-matrix s_loads -> compiler batches them
//    as s_load_dwordx8/x16 with exact counts, hidden under FMAs.
//  - No barriers, no staging phase; occupancy capped by VGPR only.
//  - FMA order bit-identical to previous rounds (absmax must stay 0).
// NO launch_bounds (min-waves directive triggered scratch spilling on this
// toolchain in the earlier session -> 13x HBM traffic).
__global__ void stage2_kernel(
    const float* __restrict__ vt,     // v_template   V*3 f32
    const float* __restrict__ skin,   // skinning     V*J f32
    const float* __restrict__ la,     // local_adjust V*3 f32
    const float* __restrict__ wsA,    // A[23][12] + {s, base.xyz}  (uniform reads)
    const int* __restrict__ bsp,      // batch_size
    float* __restrict__ out)
{
    const int v = blockIdx.x * BLK + threadIdx.x;
    if (v >= V_N) return;             // V_N % 64 == 0: whole-wave granularity

    // ---- 23 independent weight loads, all in flight together ----
    const float* wp = skin + (size_t)v * J_N;
    float w[J_N];
    #pragma unroll
    for (int j = 0; j < J_N; j++) w[j] = wp[j];

    // ---- vertex + local_adjust (independent of weights; overlaps them) ----
    const float* vp = vt + (size_t)v * 3;
    const float* lp = la + (size_t)v * 3;
    const float cvx = vp[0], cvy = vp[1], cvz = vp[2];
    const float clx = lp[0], cly = lp[1], clz = lp[2];

    const float vx = cvx + 0.1f * tanhf(clx);
    const float vy = cvy + 0.1f * tanhf(cly);
    const float vz = cvz + 0.1f * tanhf(clz);

    // ---- blend the 23 joint transforms (A rows via s_load only) ----
    float acc[12];
    #pragma unroll
    for (int k = 0; k < 12; k++) acc[k] = 0.f;
    #pragma unroll
    for (int j = 0; j < J_N; j++) {
        const float wj = w[j];
        const float* Aj = wsA + j * 12;   // uniform address -> s_load, 0 VGPRs
        #pragma unroll
        for (int k = 0; k < 12; k++) acc[k] = fmaf(wj, Aj[k], acc[k]);
    }

    const float px = acc[0]*vx + acc[1]*vy + acc[2]*vz  + acc[3];
    const float py = acc[4]*vx + acc[5]*vy + acc[6]*vz  + acc[7];
    const float pz = acc[8]*vx + acc[9]*vy + acc[10]*vz + acc[11];
    const float sc = wsA[276];            // uniform
    const float ox = fmaf(sc, px, wsA[277]);
    const float oy = fmaf(sc, py, wsA[278]);
    const float oz = fmaf(sc, pz, wsA[279]);

    const int bsz = bsp[0];
    float* ob = out + (size_t)v * 3;
    for (int b = 0; b < bsz; b++) {
        ob[0] = ox; ob[1] = oy; ob[2] = oz;   // dwordx3, coalesced
        ob += 3000000;                        // V*3 floats per batch copy
    }
    float* oe = out + OUT_LA + (size_t)v * 3; // local_adjust passthrough
    oe[0] = clx; oe[1] = cly; oe[2] = clz;
}

extern "C" void kernel_launch(void* const* d_in, const int* in_sizes, int n_in,
                              void* d_out, int out_size, void* d_ws, size_t ws_size,
                              hipStream_t stream) {
    const float* vt   = (const float*)d_in[0];
    const float* skin = (const float*)d_in[1];
    const float* jr   = (const float*)d_in[2];
    const float* j0   = (const float*)d_in[3];
    const float* j1   = (const float*)d_in[4];
    const float* j2   = (const float*)d_in[5];
    const float* j3   = (const float*)d_in[6];
    const float* j4   = (const float*)d_in[7];
    const float* j5   = (const float*)d_in[8];
    const float* j12  = (const float*)d_in[9];
    const float* j13  = (const float*)d_in[10];
    const float* la   = (const float*)d_in[11];
    const float* disp = (const float*)d_in[12];
    const float* sc   = (const float*)d_in[13];
    const float* loc  = (const float*)d_in[14];
    const int* bs     = (const int*)d_in[15];

    float* wsA = (float*)d_ws;
    float* out = (float*)d_out;

    stage1_kernel<<<1, 128, 0, stream>>>(jr, j0, j1, j2, j3, j4, j5, j12, j13,
                                         disp, sc, loc, wsA, out);
    stage2_kernel<<<(V_N + BLK - 1) / BLK, BLK, 0, stream>>>(vt, skin, la, wsA, bs, out);
}